// Round 1
// baseline (833.884 us; speedup 1.0000x reference)
//
#include <hip/hip_runtime.h>
#include <math.h>

constexpr int B_ = 8192;
constexpr int T_ = 512;

__device__ __forceinline__ float sp_(float x) {
    // stable softplus, matches jax.nn.softplus: max(x,0) + log1p(exp(-|x|))
    return fmaxf(x, 0.0f) + log1pf(expf(-fabsf(x)));
}
__device__ __forceinline__ float sg_(float x) {
    return 1.0f / (1.0f + expf(-x));
}
__device__ __forceinline__ float clipf(float x, float lo, float hi) {
    return fminf(fmaxf(x, lo), hi);
}

__global__ __launch_bounds__(64) void castro_scan(
    const float* __restrict__ in,   // [B, T, 8]  (actions[0:4], rewards[4:8])
    const float* __restrict__ p,    // [13]
    float* __restrict__ out)        // [B, T, 4]
{
    const int b = blockIdx.x * 64 + threadIdx.x;
    if (b >= B_) return;

    // ---- parameter transform (cheap, done per-thread; all L2/L1 cached) ----
    const float beta_r = clipf(sp_(p[0]), 0.01f, 20.0f);
    const float lapse  = clipf(sg_(p[1]), 0.01f, 0.99f);
    const float prior  = clipf(sp_(p[2]), 0.01f, 0.99f);
    const float alpha  = clipf(sg_(p[3]), 0.01f, 0.99f);
    const float decay  = clipf(sg_(p[4]), 0.01f, 0.99f);
    const float ab1    = p[5];
    const float ab2    = p[6];
    const float pers   = sp_(p[7]);
    const float sw     = p[8];
    const float gamma  = sp_(p[10]);
    const float temp   = clipf(sp_(p[11]) + 1e-6f, 1e-6f, 100.0f);
    const float beta_p = sp_(p[12]);

    const float brt = beta_r / temp;      // beta_r * q / temp  ->  brt * q
    const float l4  = lapse * 0.25f;      // lapse / A
    const float oml = 1.0f - lapse;

    // ---- carry state, all in registers, statically indexed ----
    float q0 = prior, q1 = prior, q2 = prior, q3 = prior;
    float c0 = 0.f, c1 = 0.f, c2 = 0.f, c3 = 0.f;   // cum
    int   oldc = -1;
    float tsls = 0.0f;
    float expl = alpha;

    const float4* ip = reinterpret_cast<const float4*>(in + (size_t)b * T_ * 8);
    float4*       op = reinterpret_cast<float4*>(out + (size_t)b * T_ * 4);

    for (int t = 0; t < T_; ++t) {
        const float4 a = ip[2 * t];       // one-hot action
        const float4 r = ip[2 * t + 1];   // broadcast reward

        // cc = argmax(a); a is exactly one-hot {0.0, 1.0}
        const int cc = a.y > 0.5f ? 1 : (a.z > 0.5f ? 2 : (a.w > 0.5f ? 3 : 0));
        const float rv = a.x * r.x + a.y * r.y + a.z * r.z + a.w * r.w;

        // q[cc] += (rv - gamma*(1-rv) - q[cc])  ==  full overwrite
        const float target = rv - gamma * (1.0f - rv);

        const bool same = (cc == oldc);
        tsls = same ? (tsls + 1.0f) : 0.0f;
        expl *= (1.0f - 1e-3f);

        if      (cc == 0) { q0 = target; c0 += 1.0f; }
        else if (cc == 1) { q1 = target; c1 += 1.0f; }
        else if (cc == 2) { q2 = target; c2 += 1.0f; }
        else              { q3 = target; c3 += 1.0f; }

        // mean-mixing exploration + decay
        const float qm = 0.25f * (q0 + q1 + q2 + q3);
        const float e  = expl, om = 1.0f - expl;
        q0 = (om * q0 + e * qm) * decay;
        q1 = (om * q1 + e * qm) * decay;
        q2 = (om * q2 + e * qm) * decay;
        q3 = (om * q3 + e * qm) * decay;

        // softmax logits input
        const float s0 = brt * q0 + beta_p * log1pf(c0);
        const float s1 = brt * q1 + beta_p * log1pf(c1);
        const float s2 = brt * q2 + beta_p * log1pf(c2);
        const float s3 = brt * q3 + beta_p * log1pf(c3);
        const float m  = fmaxf(fmaxf(s0, s1), fmaxf(s2, s3));
        const float e0 = expf(s0 - m);
        const float e1 = expf(s1 - m);
        const float e2 = expf(s2 - m);
        const float e3 = expf(s3 - m);
        const float iz = oml / (e0 + e1 + e2 + e3);

        // probs = oml * softmax + lapse/4 ; logits = log(probs)
        float l0 = logf(e0 * iz + l4);
        float l1 = logf(e1 * iz + l4);
        float l2 = logf(e2 * iz + l4);
        float l3 = logf(e3 * iz + l4);

        // bonus terms
        const float bcc = (same ? pers : sw) + logf(tsls + 1.0f);
        const int cc2 = cc ^ 2;   // (cc + 2) % 4
        l0 += (cc == 0 ? bcc : 0.0f) + (oldc == 0 ? ab1 : 0.0f) + (cc2 == 0 ? ab2 : 0.0f);
        l1 += (cc == 1 ? bcc : 0.0f) + (oldc == 1 ? ab1 : 0.0f) + (cc2 == 1 ? ab2 : 0.0f);
        l2 += (cc == 2 ? bcc : 0.0f) + (oldc == 2 ? ab1 : 0.0f) + (cc2 == 2 ? ab2 : 0.0f);
        l3 += (cc == 3 ? bcc : 0.0f) + (oldc == 3 ? ab1 : 0.0f) + (cc2 == 3 ? ab2 : 0.0f);

        op[t] = make_float4(l0, l1, l2, l3);
        oldc = cc;
    }
}

extern "C" void kernel_launch(void* const* d_in, const int* in_sizes, int n_in,
                              void* d_out, int out_size, void* d_ws, size_t ws_size,
                              hipStream_t stream) {
    const float* inputs = (const float*)d_in[0];   // [8192, 512, 8] f32
    const float* params = (const float*)d_in[1];   // [13] f32
    float* out = (float*)d_out;                    // [8192, 512, 4] f32

    // one thread per session; 64-thread blocks -> 128 blocks spread across CUs
    castro_scan<<<dim3(B_ / 64), dim3(64), 0, stream>>>(inputs, params, out);
}

// Round 2
// 252.195 us; speedup vs baseline: 3.3065x; 3.3065x over previous
//
#include <hip/hip_runtime.h>
#include <math.h>

constexpr int B_ = 8192;
constexpr int T_ = 512;
constexpr int U_ = 8;   // software-pipeline chunk (all indices compile-time)

__device__ __forceinline__ float sp_(float x) {
    // stable softplus, matches jax.nn.softplus: max(x,0) + log1p(exp(-|x|))
    return fmaxf(x, 0.0f) + log1pf(expf(-fabsf(x)));
}
__device__ __forceinline__ float sg_(float x) {
    return 1.0f / (1.0f + expf(-x));
}
__device__ __forceinline__ float clipf(float x, float lo, float hi) {
    return fminf(fmaxf(x, lo), hi);
}
__device__ __forceinline__ float sel(bool c, float a, float b) {
    return c ? a : b;   // v_cndmask
}

__global__ __launch_bounds__(64, 1) void castro_scan(
    const float* __restrict__ in,   // [B, T, 8]  (actions[0:4], rewards[4:8])
    const float* __restrict__ p,    // [13]
    float* __restrict__ out)        // [B, T, 4]
{
    const int b = blockIdx.x * 64 + threadIdx.x;
    if (b >= B_) return;

    // ---- parameter transform ----
    const float beta_r = clipf(sp_(p[0]), 0.01f, 20.0f);
    const float lapse  = clipf(sg_(p[1]), 0.01f, 0.99f);
    const float prior  = clipf(sp_(p[2]), 0.01f, 0.99f);
    const float alpha  = clipf(sg_(p[3]), 0.01f, 0.99f);
    const float decay  = clipf(sg_(p[4]), 0.01f, 0.99f);
    const float ab1    = p[5];
    const float ab2    = p[6];
    const float pers   = sp_(p[7]);
    const float sw     = p[8];
    const float gamma  = sp_(p[10]);
    const float temp   = clipf(sp_(p[11]) + 1e-6f, 1e-6f, 100.0f);
    const float beta_p = sp_(p[12]);

    const float brt = beta_r / temp;
    const float l4  = lapse * 0.25f;
    const float oml = 1.0f - lapse;

    // ---- carry state (registers, statically indexed) ----
    float q0 = prior, q1 = prior, q2 = prior, q3 = prior;
    float c0 = 0.f, c1 = 0.f, c2 = 0.f, c3 = 0.f;
    int   oldc = -1;
    float tsls = 0.0f;
    float expl = alpha;

    const float4* __restrict__ ip = reinterpret_cast<const float4*>(in + (size_t)b * T_ * 8);
    float4*       __restrict__ op = reinterpret_cast<float4*>(out + (size_t)b * T_ * 4);

    // double-buffered register prefetch
    float4 ca[U_], cr[U_], na[U_], nr[U_];
#pragma unroll
    for (int u = 0; u < U_; ++u) { ca[u] = ip[2 * u]; cr[u] = ip[2 * u + 1]; }

    for (int base = 0; base < T_; base += U_) {
        // issue next chunk's loads up front (redundant reload on last chunk, harmless)
        const int nbase = (base + U_ < T_) ? (base + U_) : base;
#pragma unroll
        for (int u = 0; u < U_; ++u) {
            na[u] = ip[2 * (nbase + u)];
            nr[u] = ip[2 * (nbase + u) + 1];
        }

#pragma unroll
        for (int u = 0; u < U_; ++u) {
            const float4 a = ca[u];
            const float4 r = cr[u];

            const int cc = a.y > 0.5f ? 1 : (a.z > 0.5f ? 2 : (a.w > 0.5f ? 3 : 0));
            const float rv = fmaf(a.x, r.x, fmaf(a.y, r.y, fmaf(a.z, r.z, a.w * r.w)));

            // q[cc] = rv - gamma*(1-rv)   (full overwrite)
            const float target = rv - gamma * (1.0f - rv);

            const bool same = (cc == oldc);
            tsls = sel(same, tsls + 1.0f, 0.0f);
            expl *= (1.0f - 1e-3f);

            const bool i0 = (cc == 0), i1 = (cc == 1), i2 = (cc == 2), i3 = (cc == 3);
            q0 = sel(i0, target, q0);  c0 += sel(i0, 1.0f, 0.0f);
            q1 = sel(i1, target, q1);  c1 += sel(i1, 1.0f, 0.0f);
            q2 = sel(i2, target, q2);  c2 += sel(i2, 1.0f, 0.0f);
            q3 = sel(i3, target, q3);  c3 += sel(i3, 1.0f, 0.0f);

            // mean-mix + decay
            const float qm = 0.25f * ((q0 + q1) + (q2 + q3));
            const float e  = expl, om = 1.0f - expl;
            q0 = fmaf(om, q0, e * qm) * decay;
            q1 = fmaf(om, q1, e * qm) * decay;
            q2 = fmaf(om, q2, e * qm) * decay;
            q3 = fmaf(om, q3, e * qm) * decay;

            // softmax inputs (log1p(c) == log(1+c) exactly: c integer-valued)
            const float s0 = fmaf(brt, q0, beta_p * __logf(1.0f + c0));
            const float s1 = fmaf(brt, q1, beta_p * __logf(1.0f + c1));
            const float s2 = fmaf(brt, q2, beta_p * __logf(1.0f + c2));
            const float s3 = fmaf(brt, q3, beta_p * __logf(1.0f + c3));
            const float m  = fmaxf(fmaxf(s0, s1), fmaxf(s2, s3));
            const float e0 = __expf(s0 - m);
            const float e1 = __expf(s1 - m);
            const float e2 = __expf(s2 - m);
            const float e3 = __expf(s3 - m);
            const float iz = oml / ((e0 + e1) + (e2 + e3));

            float l0 = __logf(fmaf(e0, iz, l4));
            float l1 = __logf(fmaf(e1, iz, l4));
            float l2 = __logf(fmaf(e2, iz, l4));
            float l3 = __logf(fmaf(e3, iz, l4));

            // bonuses
            const float bcc = sel(same, pers, sw) + __logf(tsls + 1.0f);
            const int cc2 = cc ^ 2;   // (cc + 2) % 4
            l0 += sel(i0, bcc, 0.0f) + sel(oldc == 0, ab1, 0.0f) + sel(cc2 == 0, ab2, 0.0f);
            l1 += sel(i1, bcc, 0.0f) + sel(oldc == 1, ab1, 0.0f) + sel(cc2 == 1, ab2, 0.0f);
            l2 += sel(i2, bcc, 0.0f) + sel(oldc == 2, ab1, 0.0f) + sel(cc2 == 2, ab2, 0.0f);
            l3 += sel(i3, bcc, 0.0f) + sel(oldc == 3, ab1, 0.0f) + sel(cc2 == 3, ab2, 0.0f);

            op[base + u] = make_float4(l0, l1, l2, l3);
            oldc = cc;
        }

#pragma unroll
        for (int u = 0; u < U_; ++u) { ca[u] = na[u]; cr[u] = nr[u]; }
    }
}

extern "C" void kernel_launch(void* const* d_in, const int* in_sizes, int n_in,
                              void* d_out, int out_size, void* d_ws, size_t ws_size,
                              hipStream_t stream) {
    const float* inputs = (const float*)d_in[0];   // [8192, 512, 8] f32
    const float* params = (const float*)d_in[1];   // [13] f32
    float* out = (float*)d_out;                    // [8192, 512, 4] f32

    castro_scan<<<dim3(B_ / 64), dim3(64), 0, stream>>>(inputs, params, out);
}